// Round 3
// baseline (736.242 us; speedup 1.0000x reference)
//
#include <hip/hip_runtime.h>
#include <math.h>

#define VOCAB   65536
#define HDIM    512
#define MLEN    16
#define NWORDS  8192
#define IHDIM   128      // char emb dim / LSTM input
#define HHDIM   256      // hidden per direction

#define TMW 64           // words per LSTM block (doubled: halves W_hh L2 re-stream)
#define TP  32           // words per projection block (reverted to proven r0 value)

// workspace byte offsets
#define B_WHH 0u          // 1 MB: [2][8 kt][64 ntg][64 lane] uint4 f16 W_hh B-frags
#define B_GX2 1048576u    // 4 MB: [2][256 cid][512 tid] uint4 = 8 f16 (j = g*2+c)
#define B_PBF 5242880u    // 512 KB: [16 kt][32 nt][64 lane] uint4 f16 proj B-frags
#define B_PBB 5767168u    // 2 KB: proj bias f32[512]
#define B_CHE 5769216u    // 8 MB: [8192][512] f16 char-path embeddings
#define B_INT 14157824u   // ints: [0..15] cnt, [16..31] offs, [32..47] cursor, [48] total, [64..] sorted

typedef _Float16 f16x8 __attribute__((ext_vector_type(8)));
typedef float    f32x4 __attribute__((ext_vector_type(4)));
union U4H8 { uint4 u; f16x8 h; _Float16 e[8]; };

__device__ __forceinline__ unsigned packh2(float lo, float hi) {
    union { _Float16 h[2]; unsigned u; } v;
    v.h[0] = (_Float16)lo; v.h[1] = (_Float16)hi;
    return v.u;
}

__device__ __forceinline__ float sigf(float x)  { return 1.0f / (1.0f + __expf(-x)); }
__device__ __forceinline__ float tanh_f(float x){ return 1.0f - 2.0f / (__expf(2.0f * x) + 1.0f); }

// lgkmcnt(0)-only wait (no vmcnt drain), fenced against compiler reordering
#define LGKM0()   do { __builtin_amdgcn_sched_barrier(0); __builtin_amdgcn_s_waitcnt(0xC07F); \
                       __builtin_amdgcn_sched_barrier(0); } while (0)
#define SCHED0()  __builtin_amdgcn_sched_barrier(0)

// ---- pack W_hh B-frags, proj B-frags, proj bias ----
__global__ void prep_k(const float* __restrict__ whhf, const float* __restrict__ whhb,
                       const float* __restrict__ projw, const float* __restrict__ projb,
                       char* __restrict__ wsb) {
    int i = blockIdx.x * blockDim.x + threadIdx.x;
    if (i < 65536) {   // 2 dirs * 8 kt * 64 ntg * 64 lanes
        int dir = i >> 15, r = i & 32767, kt = r >> 12, r2 = r & 4095, ntg = r2 >> 6, lane = r2 & 63;
        const float* whh = dir ? whhb : whhf;
        int n  = ntg * 16 + (lane & 15);
        int k0 = kt * 32 + (lane >> 4) * 8;
        unsigned q[4];
        #pragma unroll
        for (int jj = 0; jj < 4; ++jj)
            q[jj] = packh2(whh[n * HHDIM + k0 + 2 * jj], whh[n * HHDIM + k0 + 2 * jj + 1]);
        ((uint4*)(wsb + B_WHH))[i] = make_uint4(q[0], q[1], q[2], q[3]);
    }
    if (i < 32768) {   // 16 kt * 32 nt * 64 lanes (proj: B[k][j] = projw[j][k])
        int kt = i >> 11, r = i & 2047, nt = r >> 6, lane = r & 63;
        int j  = nt * 16 + (lane & 15);
        int k0 = kt * 32 + (lane >> 4) * 8;
        unsigned q[4];
        #pragma unroll
        for (int jj = 0; jj < 4; ++jj)
            q[jj] = packh2(projw[j * HDIM + k0 + 2 * jj], projw[j * HDIM + k0 + 2 * jj + 1]);
        ((uint4*)(wsb + B_PBF))[i] = make_uint4(q[0], q[1], q[2], q[3]);
    }
    if (i < 512) ((float*)(wsb + B_PBB))[i] = projb[i];
}

// ---- gxc2[dir][cid][tid]: 4 cids per block, W_ih row reused across cids ----
__global__ void gxc_k(const float* __restrict__ wihf, const float* __restrict__ wihb,
                      const float* __restrict__ bihf, const float* __restrict__ bhhf,
                      const float* __restrict__ bihb, const float* __restrict__ bhhb,
                      const float* __restrict__ chemb, char* __restrict__ wsb) {
    const int dir = blockIdx.x >> 6, grp = blockIdx.x & 63;   // 64 groups of 4 cids
    const int tid = threadIdx.x;
    __shared__ __align__(16) float emb[4][IHDIM];   // 2 KB
    __shared__ float gxl[4][1024];                  // 16 KB
    for (int i = tid; i < 4 * IHDIM; i += 256)
        emb[i >> 7][i & 127] = chemb[(grp * 4 + (i >> 7)) * IHDIM + (i & 127)];
    __syncthreads();
    const float* wih = dir ? wihb : wihf;
    const float* bih = dir ? bihb : bihf;
    const float* bhh = dir ? bhhb : bhhf;
    #pragma unroll
    for (int p = 0; p < 4; ++p) {
        int n = tid + p * 256;
        float base = bih[n] + bhh[n];
        float a0 = base, a1 = base, a2 = base, a3 = base;
        const float4* w4 = (const float4*)(wih + n * IHDIM);
        #pragma unroll 4
        for (int k4 = 0; k4 < 32; ++k4) {
            float4 w = w4[k4];
            float4 e0 = ((const float4*)emb[0])[k4];
            float4 e1 = ((const float4*)emb[1])[k4];
            float4 e2 = ((const float4*)emb[2])[k4];
            float4 e3 = ((const float4*)emb[3])[k4];
            a0 = fmaf(w.x, e0.x, fmaf(w.y, e0.y, fmaf(w.z, e0.z, fmaf(w.w, e0.w, a0))));
            a1 = fmaf(w.x, e1.x, fmaf(w.y, e1.y, fmaf(w.z, e1.z, fmaf(w.w, e1.w, a1))));
            a2 = fmaf(w.x, e2.x, fmaf(w.y, e2.y, fmaf(w.z, e2.z, fmaf(w.w, e2.w, a2))));
            a3 = fmaf(w.x, e3.x, fmaf(w.y, e3.y, fmaf(w.z, e3.z, fmaf(w.w, e3.w, a3))));
        }
        gxl[0][n] = a0; gxl[1][n] = a1; gxl[2][n] = a2; gxl[3][n] = a3;
    }
    __syncthreads();
    uint4* outp = (uint4*)(wsb + B_GX2) + ((size_t)dir * 256 + grp * 4) * 512;
    for (int i = tid; i < 4 * 512; i += 256) {
        int cid4 = i >> 9, tid2 = i & 511;
        int wv2 = tid2 >> 6, col2 = tid2 & 15;   // quad bits replicate (word-select happens in lstm_k)
        U4H8 v;
        #pragma unroll
        for (int g = 0; g < 4; ++g)
            #pragma unroll
            for (int c = 0; c < 2; ++c)
                v.e[g * 2 + c] = (_Float16)gxl[cid4][g * 256 + wv2 * 32 + c * 16 + col2];
        outp[(size_t)cid4 * 512 + tid2] = v.u;
    }
}

// ---- counting sort of OOV word indices by length (descending) ----
__global__ void count_k(const int* __restrict__ is_oov, const int* __restrict__ lens,
                        int* __restrict__ ip) {
    int n = blockIdx.x * blockDim.x + threadIdx.x;
    if (n < NWORDS && is_oov[n] > 0) atomicAdd(&ip[lens[n] - 1], 1);
}

__global__ void prefix_k(int* __restrict__ ip) {
    if (threadIdx.x == 0) {
        int total = 0;
        for (int b = 15; b >= 0; --b) { ip[16 + b] = total; ip[32 + b] = total; total += ip[b]; }
        ip[48] = total;
    }
}

__global__ void scatter_k(const int* __restrict__ is_oov, const int* __restrict__ lens,
                          int* __restrict__ ip) {
    int n = blockIdx.x * blockDim.x + threadIdx.x;
    if (n < NWORDS && is_oov[n] > 0) {
        int pos = atomicAdd(&ip[32 + lens[n] - 1], 1);
        ip[64 + pos] = n;
    }
}

// ---- MFMA BiLSTM v4: TMW=64, W_hh global->VGPR 3-slot half-kt ring, acc in AGPRs ----
// r2 post-mortem: 128-arch-VGPR cap + 176-reg demand = catastrophic spills. v4:
// (a) TMW 32->64 halves total W_hh L2 re-stream (the measured bottleneck: 13 us/step
//     streaming 512 KB/step per block for only 32 words);
// (b) arch live set ~110 (af 16 + ring 48 + cst 32 + temps); acc (128 f32) is pure
//     MFMA C/D -> AGPRs on gfx950's unified file (m97 precedent: 164v+64a coexist);
// (c) single-arg launch_bounds + amdgpu_waves_per_eu(2) -> 256-reg/wave ceiling
//     (8 waves/CU), instead of the 2-arg form that pinned 128 in r1/r2;
// (d) ring loads are register-dependent -> compiler inserts exact vmcnt; raw
//     s_barrier + lgkm-only drains keep prefetch in flight across barriers;
// (e) sorted-desc mask via block-uniform cnt_s[t] (m < cnt) kills all per-thread
//     length registers; gq consumed at activation, 2-deep mt pipeline (qa/qb named).
__global__ __launch_bounds__(512) __attribute__((amdgpu_waves_per_eu(2)))
void lstm_k(const int* __restrict__ char_ids, const int* __restrict__ lens,
            const char* __restrict__ wsb, const int* __restrict__ ip) {
    // dir-grouped XCD swizzle: XCDs 0-3 dir 0, XCDs 4-7 dir 1 -> per-XCD L2 set
    // = one dir's W_hh (512 KB) + gx2 (2 MB), L2-resident.
    const int bid = blockIdx.x;
    const int xcd = bid & 7;
    const int dir = xcd >> 2;
    const int bx  = (bid >> 3) * 4 + (xcd & 3);
    const int tid = threadIdx.x;
    const int total = ip[48];
    const int w0 = bx * TMW;
    if (w0 >= total) return;
    const int wcount = min(TMW, total - w0);
    const int* sorted = ip + 64;

    __shared__ int n_s[TMW], len_s[TMW], cnt_s[MLEN];
    __shared__ unsigned char cid_s[MLEN][TMW];
    __shared__ __align__(16) _Float16 Zh[TMW][264];     // 33.8 KB; total LDS ~35.4 KB

    if (tid < TMW) {
        int idx = w0 + min(tid, wcount - 1);
        n_s[tid] = sorted[idx];
        len_s[tid] = (tid < wcount) ? lens[sorted[idx]] : 0;
    }
    for (int i = tid; i < TMW * 132; i += 512) ((unsigned*)Zh)[i] = 0u;   // h0 = 0
    __syncthreads();
    // stage char ids (pre-reversed for bwd), as u8 (cid < 256)
    for (int s = tid; s < TMW * MLEN; s += 512) {
        int m = s >> 4, tq = s & 15;
        int L = len_s[m];
        int pos = dir ? max(L - 1 - tq, 0) : tq;
        cid_s[tq][m] = (unsigned char)char_ids[n_s[m] * MLEN + pos];
    }
    // cnt_s[t] = #words with len > t (sorted desc => active mask is m < cnt_s[t])
    if (tid < MLEN) {
        int c = 0;
        for (int w = 0; w < TMW; ++w) c += (len_s[w] > tid) ? 1 : 0;
        cnt_s[tid] = c;
    }
    const int maxlen = len_s[0];    // sorted desc

    const int wv = tid >> 6, lane = tid & 63, col = lane & 15, quad = lane >> 4;
    const int rot = bx & 7;         // kt phase rotation de-phases same-address L2 streams

    const uint4* wpg = (const uint4*)(wsb + B_WHH) + (size_t)dir * 32768;   // [kt][ntg][lane]
    const uint4* gx2 = (const uint4*)(wsb + B_GX2) + (size_t)dir * 131072;  // [cid][tid]
    const uint4* wl  = wpg + wv * 128 + lane;   // frag: wl[ktR*4096 + g*1024 + c*64]

    // cid_s/cnt_s visibility (no vmcnt drain)
    LGKM0();
    __builtin_amdgcn_s_barrier();
    SCHED0();

    uint4 ring[3][4];     // 3-slot half-kt ring (4 frags/slot), 48 VGPR
    auto issue_ph = [&](int ph, int slot) {   // half-kt ph: 4 coalesced 16B loads
        const int ktR = (((ph >> 1) & 7) + rot) & 7;
        const uint4* p = wl + (size_t)ktR * 4096;
        #pragma unroll
        for (int fi = 0; fi < 4; ++fi) {
            const int f = ((ph & 1) << 2) + fi, g = f >> 1, c = f & 1;
            ring[slot][fi] = p[g * 1024 + c * 64];
        }
    };

    float cst[2][4][4];   // [c][mt][r] cell state, 32 regs
    #pragma unroll
    for (int c = 0; c < 2; ++c)
        #pragma unroll
        for (int mt = 0; mt < 4; ++mt)
            #pragma unroll
            for (int r = 0; r < 4; ++r) cst[c][mt][r] = 0.0f;

    issue_ph(0, 0);   // prologue prefetch
    issue_ph(1, 1);

    for (int t = 0; t < maxlen; ++t) {
        f32x4 acc[4][2][4];   // [g][c][mt] — 128 f32, MFMA C/D -> AGPRs
        #pragma unroll
        for (int g = 0; g < 4; ++g)
            #pragma unroll
            for (int c = 0; c < 2; ++c)
                #pragma unroll
                for (int mt = 0; mt < 4; ++mt)
                    acc[g][c][mt] = (f32x4){0.0f, 0.0f, 0.0f, 0.0f};

        f16x8 af[4];
        #pragma unroll
        for (int ph = 0; ph < 16; ++ph) {
            const int ktR = ((ph >> 1) + rot) & 7;
            if ((ph & 1) == 0) {
                #pragma unroll
                for (int mt = 0; mt < 4; ++mt)
                    af[mt] = *(const f16x8*)&Zh[mt * 16 + col][ktR * 32 + quad * 8];
            }
            #pragma unroll
            for (int fi = 0; fi < 4; ++fi) {
                const int f = ((ph & 1) << 2) + fi, g = f >> 1, c = f & 1;
                U4H8 b; b.u = ring[ph % 3][fi];
                #pragma unroll
                for (int mt = 0; mt < 4; ++mt)
                    acc[g][c][mt] = __builtin_amdgcn_mfma_f32_16x16x32_f16(af[mt], b.h, acc[g][c][mt], 0, 0, 0);
            }
            if (ph < 14) issue_ph(ph + 2, (ph + 2) % 3);
        }
        issue_ph(0, 0);   // next step's first two half-kt (same weights)
        issue_ph(1, 1);

        // barrier 1: all waves' Zh A-reads done before h overwrite (loads stay in flight)
        SCHED0();
        __builtin_amdgcn_s_barrier();
        SCHED0();

        // activation: gq gathered here (8 kt of MFMA no longer needs acc-init residency)
        const int cnt = cnt_s[t];
        uchar4 cq[4];
        #pragma unroll
        for (int mt = 0; mt < 4; ++mt)
            cq[mt] = *(const uchar4*)&cid_s[t][mt * 16 + quad * 4];

        U4H8 qa[4], qb[4];
        #define GQ_LOAD(dst, mt_) do { \
            dst[0].u = gx2[(size_t)cq[mt_].x * 512 + tid]; \
            dst[1].u = gx2[(size_t)cq[mt_].y * 512 + tid]; \
            dst[2].u = gx2[(size_t)cq[mt_].z * 512 + tid]; \
            dst[3].u = gx2[(size_t)cq[mt_].w * 512 + tid]; } while (0)

        auto act_mt = [&](int mt, U4H8 (&q)[4]) {
            #pragma unroll
            for (int r = 0; r < 4; ++r) {
                int m = mt * 16 + quad * 4 + r;
                if (m < cnt) {
                    #pragma unroll
                    for (int c = 0; c < 2; ++c) {
                        float i_ = sigf(acc[0][c][mt][r] + (float)q[r].e[0 + c]);
                        float f_ = sigf(acc[1][c][mt][r] + (float)q[r].e[2 + c]);
                        float g_ = tanh_f(acc[2][c][mt][r] + (float)q[r].e[4 + c]);
                        float o_ = sigf(acc[3][c][mt][r] + (float)q[r].e[6 + c]);
                        float cn = f_ * cst[c][mt][r] + i_ * g_;
                        cst[c][mt][r] = cn;
                        Zh[m][wv * 32 + c * 16 + col] = (_Float16)(o_ * tanh_f(cn));
                    }
                }
            }
        };

        GQ_LOAD(qa, 0); GQ_LOAD(qb, 1);
        act_mt(0, qa);  GQ_LOAD(qa, 2);
        act_mt(1, qb);  GQ_LOAD(qb, 3);
        act_mt(2, qa);
        act_mt(3, qb);
        #undef GQ_LOAD

        // barrier 2: h writes visible before next step's A-reads (lgkm drain only)
        LGKM0();
        __builtin_amdgcn_s_barrier();
        SCHED0();
    }

    unsigned short* cheh = (unsigned short*)(wsb + B_CHE);
    for (int i = tid; i < TMW * HHDIM; i += 512) {
        int m = i >> 8, u = i & 255;
        if (m < wcount) {
            union { _Float16 h; unsigned short s; } v; v.h = Zh[m][u];
            __builtin_nontemporal_store(v.s, cheh + (size_t)n_s[m] * HDIM + dir * HHDIM + u);
        }
    }
}

// ---- select + projection via f16 MFMA: 32 words/block, 512 thr (r0-proven) ----
__global__ __launch_bounds__(512, 2)
void proj_k(const int* __restrict__ word_ids, const int* __restrict__ is_oov,
            const float* __restrict__ word_emb, const char* __restrict__ wsb,
            float* __restrict__ out) {
    const int tid = threadIdx.x;
    const int n0 = blockIdx.x * TP;
    __shared__ __align__(16) _Float16 Zp[TP][520];   // 33.3 KB

    for (int f = tid; f < TP * 128; f += 512) {      // 128 segs of 4 elems per word
        int w = f >> 7, s4 = f & 127;
        int n = n0 + w;
        if (is_oov[n] > 0) {
            ushort4 hv = ((const ushort4*)((const unsigned short*)(wsb + B_CHE) + (size_t)n * HDIM))[s4];
            *(ushort4*)&Zp[w][s4 * 4] = hv;
        } else {
            float4 v = ((const float4*)(word_emb + (size_t)word_ids[n] * HDIM))[s4];
            Zp[w][s4 * 4 + 0] = (_Float16)v.x;
            Zp[w][s4 * 4 + 1] = (_Float16)v.y;
            Zp[w][s4 * 4 + 2] = (_Float16)v.z;
            Zp[w][s4 * 4 + 3] = (_Float16)v.w;
        }
    }
    __syncthreads();

    const int wv = tid >> 6, lane = tid & 63, col = lane & 15, quad = lane >> 4;
    const float* pbb = (const float*)(wsb + B_PBB);
    f32x4 acc[4][2];
    #pragma unroll
    for (int c = 0; c < 4; ++c) {
        float b = pbb[wv * 64 + c * 16 + col];
        acc[c][0] = (f32x4){b, b, b, b};
        acc[c][1] = (f32x4){b, b, b, b};
    }

    const uint4* pbf = (const uint4*)(wsb + B_PBF);
    #pragma unroll
    for (int kt = 0; kt < 16; ++kt) {
        f16x8 af0 = *(const f16x8*)&Zp[col][kt * 32 + quad * 8];
        f16x8 af1 = *(const f16x8*)&Zp[16 + col][kt * 32 + quad * 8];
        #pragma unroll
        for (int c = 0; c < 4; ++c) {
            U4H8 b; b.u = pbf[(size_t)kt * 2048 + (wv * 4 + c) * 64 + lane];
            acc[c][0] = __builtin_amdgcn_mfma_f32_16x16x32_f16(af0, b.h, acc[c][0], 0, 0, 0);
            acc[c][1] = __builtin_amdgcn_mfma_f32_16x16x32_f16(af1, b.h, acc[c][1], 0, 0, 0);
        }
    }

    #pragma unroll
    for (int mt = 0; mt < 2; ++mt)
        #pragma unroll
        for (int r = 0; r < 4; ++r) {
            const size_t m = n0 + mt * 16 + quad * 4 + r;
            #pragma unroll
            for (int c = 0; c < 4; ++c)
                __builtin_nontemporal_store(acc[c][mt][r], &out[m * HDIM + wv * 64 + c * 16 + col]);
        }
}

extern "C" void kernel_launch(void* const* d_in, const int* in_sizes, int n_in,
                              void* d_out, int out_size, void* d_ws, size_t ws_size,
                              hipStream_t stream) {
    const int*   word_ids  = (const int*)d_in[0];
    const int*   is_oov    = (const int*)d_in[1];
    const int*   char_ids  = (const int*)d_in[2];
    const int*   char_lens = (const int*)d_in[3];
    const float* word_emb  = (const float*)d_in[4];
    const float* char_emb  = (const float*)d_in[5];
    const float* w_ih_f    = (const float*)d_in[6];
    const float* w_hh_f    = (const float*)d_in[7];
    const float* b_ih_f    = (const float*)d_in[8];
    const float* b_hh_f    = (const float*)d_in[9];
    const float* w_ih_b    = (const float*)d_in[10];
    const float* w_hh_b    = (const float*)d_in[11];
    const float* b_ih_b    = (const float*)d_in[12];
    const float* b_hh_b    = (const float*)d_in[13];
    const float* proj_w    = (const float*)d_in[14];
    const float* proj_b    = (const float*)d_in[15];
    float* out = (float*)d_out;
    char*  wsb = (char*)d_ws;
    int*   ip  = (int*)(wsb + B_INT);

    hipMemsetAsync(ip, 0, 256, stream);
    prep_k<<<256, 256, 0, stream>>>(w_hh_f, w_hh_b, proj_w, proj_b, wsb);
    gxc_k<<<128, 256, 0, stream>>>(w_ih_f, w_ih_b, b_ih_f, b_hh_f, b_ih_b, b_hh_b, char_emb, wsb);
    count_k<<<NWORDS / 256, 256, 0, stream>>>(is_oov, char_lens, ip);
    prefix_k<<<1, 64, 0, stream>>>(ip);
    scatter_k<<<NWORDS / 256, 256, 0, stream>>>(is_oov, char_lens, ip);
    lstm_k<<<256, 512, 0, stream>>>(char_ids, char_lens, wsb, ip);
    proj_k<<<NWORDS / TP, 512, 0, stream>>>(word_ids, is_oov, word_emb, wsb, out);
}

// Round 4
// 445.252 us; speedup vs baseline: 1.6535x; 1.6535x over previous
//
#include <hip/hip_runtime.h>
#include <math.h>

#define VOCAB   65536
#define HDIM    512
#define MLEN    16
#define NWORDS  8192
#define IHDIM   128      // char emb dim / LSTM input
#define HHDIM   256      // hidden per direction

#define TMW 32           // words per LSTM block (r0-proven; 256 active blocks = full machine)
#define TP  32           // words per projection block (r0-proven)

// workspace byte offsets
#define B_WHH 0u          // 1 MB: [2][8 kt][64 ntg][64 lane] uint4 f16 W_hh B-frags
#define B_GX2 1048576u    // 4 MB: [2][256 cid][512 tid] uint4 = 8 f16 (j = g*2+c)
#define B_PBF 5242880u    // 512 KB: [16 kt][32 nt][64 lane] uint4 f16 proj B-frags
#define B_PBB 5767168u    // 2 KB: proj bias f32[512]
#define B_CHE 5769216u    // 8 MB: [8192][512] f16 char-path embeddings
#define B_INT 14157824u   // ints: [0..15] cnt, [16..31] offs, [32..47] cursor, [48] total, [64..] sorted

typedef _Float16 f16x8 __attribute__((ext_vector_type(8)));
typedef float    f32x4 __attribute__((ext_vector_type(4)));
union U4H8 { uint4 u; f16x8 h; _Float16 e[8]; };

__device__ __forceinline__ unsigned packh2(float lo, float hi) {
    union { _Float16 h[2]; unsigned u; } v;
    v.h[0] = (_Float16)lo; v.h[1] = (_Float16)hi;
    return v.u;
}

__device__ __forceinline__ float sigf(float x)  { return 1.0f / (1.0f + __expf(-x)); }
__device__ __forceinline__ float tanh_f(float x){ return 1.0f - 2.0f / (__expf(2.0f * x) + 1.0f); }

// async global->LDS 16B per lane; lds base wave-uniform (writes base + lane*16)
__device__ __forceinline__ void load_lds_128(const void* g, void* l) {
    __builtin_amdgcn_global_load_lds((const __attribute__((address_space(1))) unsigned*)g,
                                     (__attribute__((address_space(3))) unsigned*)l, 16, 0, 0);
}

// s_waitcnt immediates: vmcnt bits[3:0]|[15:14], expcnt [6:4], lgkmcnt [11:8]
#define VMCNT8()  do { __builtin_amdgcn_s_waitcnt(0x0F78); __builtin_amdgcn_sched_barrier(0); } while (0)
#define LGKM0()   do { __builtin_amdgcn_sched_barrier(0); __builtin_amdgcn_s_waitcnt(0xC07F); \
                       __builtin_amdgcn_sched_barrier(0); } while (0)
#define SCHED0()  __builtin_amdgcn_sched_barrier(0)

// ---- pack W_hh B-frags, proj B-frags, proj bias ----
__global__ void prep_k(const float* __restrict__ whhf, const float* __restrict__ whhb,
                       const float* __restrict__ projw, const float* __restrict__ projb,
                       char* __restrict__ wsb) {
    int i = blockIdx.x * blockDim.x + threadIdx.x;
    if (i < 65536) {   // 2 dirs * 8 kt * 64 ntg * 64 lanes
        int dir = i >> 15, r = i & 32767, kt = r >> 12, r2 = r & 4095, ntg = r2 >> 6, lane = r2 & 63;
        const float* whh = dir ? whhb : whhf;
        int n  = ntg * 16 + (lane & 15);
        int k0 = kt * 32 + (lane >> 4) * 8;
        unsigned q[4];
        #pragma unroll
        for (int jj = 0; jj < 4; ++jj)
            q[jj] = packh2(whh[n * HHDIM + k0 + 2 * jj], whh[n * HHDIM + k0 + 2 * jj + 1]);
        ((uint4*)(wsb + B_WHH))[i] = make_uint4(q[0], q[1], q[2], q[3]);
    }
    if (i < 32768) {   // 16 kt * 32 nt * 64 lanes (proj: B[k][j] = projw[j][k])
        int kt = i >> 11, r = i & 2047, nt = r >> 6, lane = r & 63;
        int j  = nt * 16 + (lane & 15);
        int k0 = kt * 32 + (lane >> 4) * 8;
        unsigned q[4];
        #pragma unroll
        for (int jj = 0; jj < 4; ++jj)
            q[jj] = packh2(projw[j * HDIM + k0 + 2 * jj], projw[j * HDIM + k0 + 2 * jj + 1]);
        ((uint4*)(wsb + B_PBF))[i] = make_uint4(q[0], q[1], q[2], q[3]);
    }
    if (i < 512) ((float*)(wsb + B_PBB))[i] = projb[i];
}

// ---- gxc2[dir][cid][tid]: 4 cids per block, W_ih row reused across cids ----
__global__ void gxc_k(const float* __restrict__ wihf, const float* __restrict__ wihb,
                      const float* __restrict__ bihf, const float* __restrict__ bhhf,
                      const float* __restrict__ bihb, const float* __restrict__ bhhb,
                      const float* __restrict__ chemb, char* __restrict__ wsb) {
    const int dir = blockIdx.x >> 6, grp = blockIdx.x & 63;   // 64 groups of 4 cids
    const int tid = threadIdx.x;
    __shared__ __align__(16) float emb[4][IHDIM];   // 2 KB
    __shared__ float gxl[4][1024];                  // 16 KB
    for (int i = tid; i < 4 * IHDIM; i += 256)
        emb[i >> 7][i & 127] = chemb[(grp * 4 + (i >> 7)) * IHDIM + (i & 127)];
    __syncthreads();
    const float* wih = dir ? wihb : wihf;
    const float* bih = dir ? bihb : bihf;
    const float* bhh = dir ? bhhb : bhhf;
    #pragma unroll
    for (int p = 0; p < 4; ++p) {
        int n = tid + p * 256;
        float base = bih[n] + bhh[n];
        float a0 = base, a1 = base, a2 = base, a3 = base;
        const float4* w4 = (const float4*)(wih + n * IHDIM);
        #pragma unroll 4
        for (int k4 = 0; k4 < 32; ++k4) {
            float4 w = w4[k4];
            float4 e0 = ((const float4*)emb[0])[k4];
            float4 e1 = ((const float4*)emb[1])[k4];
            float4 e2 = ((const float4*)emb[2])[k4];
            float4 e3 = ((const float4*)emb[3])[k4];
            a0 = fmaf(w.x, e0.x, fmaf(w.y, e0.y, fmaf(w.z, e0.z, fmaf(w.w, e0.w, a0))));
            a1 = fmaf(w.x, e1.x, fmaf(w.y, e1.y, fmaf(w.z, e1.z, fmaf(w.w, e1.w, a1))));
            a2 = fmaf(w.x, e2.x, fmaf(w.y, e2.y, fmaf(w.z, e2.z, fmaf(w.w, e2.w, a2))));
            a3 = fmaf(w.x, e3.x, fmaf(w.y, e3.y, fmaf(w.z, e3.z, fmaf(w.w, e3.w, a3))));
        }
        gxl[0][n] = a0; gxl[1][n] = a1; gxl[2][n] = a2; gxl[3][n] = a3;
    }
    __syncthreads();
    uint4* outp = (uint4*)(wsb + B_GX2) + ((size_t)dir * 256 + grp * 4) * 512;
    for (int i = tid; i < 4 * 512; i += 256) {
        int cid4 = i >> 9, tid2 = i & 511;
        int wv2 = tid2 >> 6, col2 = tid2 & 15;
        U4H8 v;
        #pragma unroll
        for (int g = 0; g < 4; ++g)
            #pragma unroll
            for (int c = 0; c < 2; ++c)
                v.e[g * 2 + c] = (_Float16)gxl[cid4][g * 256 + wv2 * 32 + c * 16 + col2];
        outp[(size_t)cid4 * 512 + tid2] = v.u;
    }
}

// ---- counting sort of OOV word indices by length (descending) ----
__global__ void count_k(const int* __restrict__ is_oov, const int* __restrict__ lens,
                        int* __restrict__ ip) {
    int n = blockIdx.x * blockDim.x + threadIdx.x;
    if (n < NWORDS && is_oov[n] > 0) atomicAdd(&ip[lens[n] - 1], 1);
}

__global__ void prefix_k(int* __restrict__ ip) {
    if (threadIdx.x == 0) {
        int total = 0;
        for (int b = 15; b >= 0; --b) { ip[16 + b] = total; ip[32 + b] = total; total += ip[b]; }
        ip[48] = total;
    }
}

__global__ void scatter_k(const int* __restrict__ is_oov, const int* __restrict__ lens,
                          int* __restrict__ ip) {
    int n = blockIdx.x * blockDim.x + threadIdx.x;
    if (n < NWORDS && is_oov[n] > 0) {
        int pos = atomicAdd(&ip[32 + lens[n] - 1], 1);
        ip[64 + pos] = n;
    }
}

// ---- MFMA BiLSTM v5: r0 skeleton + raw barriers + deferred gq + dir-L2 swizzle ----
// r3 post-mortem: 128-VGPR wall is HARD (3 rounds of spill evidence); TMW=64 also
// halves the active grid (half machine idle). v5 returns to the proven r0 structure
// (TMW=32, LDS staging, 128 regs, full 256-block machine) and removes only the
// measured stalls, at zero register delta:
//  (1) __syncthreads -> raw s_barrier (+lgkm-only where ds_writes must publish):
//      the two per-step vmcnt(0) drains no longer empty the DMA prefetch queue.
//  (2) gq gather for step t+1 issued at END of activation (acc regs dead there ->
//      no pressure bump); latency hides under barrier-2 instead of stalling t+1.
//  (3) dir-grouped XCD swizzle: per-XCD L2 set = one dir's W_hh + gx2 = 2.5 MB,
//      fits the 4 MB XCD L2 (r0 thrashed: 5 MB).
__global__ __launch_bounds__(512, 2)
void lstm_k(const int* __restrict__ char_ids, const int* __restrict__ lens,
            const char* __restrict__ wsb, const int* __restrict__ ip) {
    const int bid = blockIdx.x;
    const int xcd = bid & 7;
    const int dir = xcd >> 2;                     // XCDs 0-3: dir 0, XCDs 4-7: dir 1
    const int bx  = (bid >> 3) * 4 + (xcd & 3);   // bijective within each dir
    const int tid = threadIdx.x;
    const int total = ip[48];
    const int w0 = bx * TMW;
    if (w0 >= total) return;
    const int wcount = min(TMW, total - w0);
    const int* sorted = ip + 64;

    __shared__ int n_s[TMW], len_s[TMW], cnt_s[MLEN];
    __shared__ unsigned char cid_s[MLEN][TMW];
    __shared__ __align__(16) _Float16 Zh[TMW][264];     // 16.9 KB
    __shared__ __align__(16) uint4 wbuf[8][2][512];     // 128 KB: [wave][buf][gc*64+lane]

    if (tid < TMW) {
        int idx = w0 + min(tid, wcount - 1);
        n_s[tid] = sorted[idx];
        len_s[tid] = (tid < wcount) ? lens[sorted[idx]] : 0;
    }
    for (int i = tid; i < TMW * 132; i += 512) ((unsigned*)Zh)[i] = 0u;   // h0 = 0
    __syncthreads();
    {   // stage char ids (pre-reversed for bwd), u8 (cid < 256)
        int m = tid >> 4, tq = tid & 15;
        int L = len_s[m];
        int pos = dir ? max(L - 1 - tq, 0) : tq;
        cid_s[tq][m] = (unsigned char)char_ids[n_s[m] * MLEN + pos];
    }
    // cnt_s[t] = #words with len > t (sorted desc => active mask is m < cnt_s[t])
    if (tid < MLEN) {
        int c = 0;
        #pragma unroll
        for (int w = 0; w < TMW; ++w) c += (len_s[w] > tid) ? 1 : 0;
        cnt_s[tid] = c;
    }
    const int maxlen = len_s[0];    // sorted desc

    const int wv = tid >> 6, lane = tid & 63, col = lane & 15, quad = lane >> 4;

    const uint4* wpg = (const uint4*)(wsb + B_WHH) + (size_t)dir * 32768;   // [kt][ntg][lane]
    const uint4* gx2 = (const uint4*)(wsb + B_GX2) + (size_t)dir * 131072;  // [cid][tid]

    auto stage = [&](int kt, int buf) {   // wave-private: 8 chunks of 1 KB
        #pragma unroll
        for (int gc = 0; gc < 8; ++gc) {
            int ntg = (gc >> 1) * 16 + wv * 2 + (gc & 1);
            load_lds_128(wpg + (kt * 4096 + ntg * 64 + lane), &wbuf[wv][buf][gc * 64]);
        }
    };

    U4H8 gq[2][4];   // gather for the UPCOMING step (issued at end of prev activation)
    auto issue_gq = [&](int t) {
        #pragma unroll
        for (int mt = 0; mt < 2; ++mt)
            #pragma unroll
            for (int r = 0; r < 4; ++r)
                gq[mt][r].u = gx2[(size_t)cid_s[t][mt * 16 + quad * 4 + r] * 512 + tid];
    };

    float cst[2][2][4];   // [c][mt][r]
    #pragma unroll
    for (int c = 0; c < 2; ++c)
        #pragma unroll
        for (int mt = 0; mt < 2; ++mt)
            #pragma unroll
            for (int r = 0; r < 4; ++r) cst[c][mt][r] = 0.0f;

    // publish cid_s/cnt_s/Zh (lgkm only), then prologue prefetch
    LGKM0();
    __builtin_amdgcn_s_barrier();
    SCHED0();
    stage(0, 0);
    issue_gq(0);
    SCHED0();

    for (int t = 0; t < maxlen; ++t) {
        // acc init from gq (r0 form). gq was issued >= one barrier ago; the
        // compiler's vmcnt wait here also confirms stage(0)'s slice landed.
        f32x4 acc[4][2][2];   // [g][c][mt]
        #pragma unroll
        for (int g = 0; g < 4; ++g)
            #pragma unroll
            for (int c = 0; c < 2; ++c)
                #pragma unroll
                for (int mt = 0; mt < 2; ++mt) {
                    f32x4 a;
                    #pragma unroll
                    for (int r = 0; r < 4; ++r) a[r] = (float)gq[mt][r].e[g * 2 + c];
                    acc[g][c][mt] = a;
                }
        SCHED0();

        #pragma unroll
        for (int kt = 0; kt < 8; ++kt) {
            const int buf = kt & 1;
            stage((kt + 1) & 7, buf ^ 1);               // prefetch next slice (kt=7 -> next step's s0)
            VMCNT8();                                   // cur buf's DMA done (16 out -> wait to 8)
            f16x8 af0 = *(const f16x8*)&Zh[col][kt * 32 + quad * 8];
            f16x8 af1 = *(const f16x8*)&Zh[16 + col][kt * 32 + quad * 8];
            #pragma unroll
            for (int g = 0; g < 4; ++g)
                #pragma unroll
                for (int c = 0; c < 2; ++c) {
                    U4H8 b; b.u = wbuf[wv][buf][(g * 2 + c) * 64 + lane];
                    acc[g][c][0] = __builtin_amdgcn_mfma_f32_16x16x32_f16(af0, b.h, acc[g][c][0], 0, 0, 0);
                    acc[g][c][1] = __builtin_amdgcn_mfma_f32_16x16x32_f16(af1, b.h, acc[g][c][1], 0, 0, 0);
                }
        }

        // barrier 1: all waves' Zh A-reads are complete (each ds_read was consumed
        // by its MFMA behind a compiler lgkm wait). Raw barrier: DMA prefetch for
        // the next step stays in flight.
        SCHED0();
        __builtin_amdgcn_s_barrier();
        SCHED0();

        const int cnt = cnt_s[t];
        #pragma unroll
        for (int mt = 0; mt < 2; ++mt)
            #pragma unroll
            for (int r = 0; r < 4; ++r) {
                const int m = mt * 16 + quad * 4 + r;
                if (m < cnt) {
                    #pragma unroll
                    for (int c = 0; c < 2; ++c) {
                        float i_ = sigf(acc[0][c][mt][r]);
                        float f_ = sigf(acc[1][c][mt][r]);
                        float g_ = tanh_f(acc[2][c][mt][r]);
                        float o_ = sigf(acc[3][c][mt][r]);
                        float cn = f_ * cst[c][mt][r] + i_ * g_;
                        cst[c][mt][r] = cn;
                        Zh[m][wv * 32 + c * 16 + col] = (_Float16)(o_ * tanh_f(cn));
                    }
                }
            }

        // issue next step's gather here: acc is dead -> no register-pressure bump;
        // latency hides under barrier-2 and the other waves' activation work.
        { int tn = (t + 1 < maxlen) ? t + 1 : t; issue_gq(tn); }

        // barrier 2: h writes visible before next step's A-reads (lgkm drain only;
        // gq + stage loads remain in flight).
        LGKM0();
        __builtin_amdgcn_s_barrier();
        SCHED0();
    }

    unsigned short* cheh = (unsigned short*)(wsb + B_CHE);
    for (int i = tid; i < TMW * HHDIM; i += 512) {
        int m = i >> 8, u = i & 255;
        if (m < wcount) {
            union { _Float16 h; unsigned short s; } v; v.h = Zh[m][u];
            __builtin_nontemporal_store(v.s, cheh + (size_t)n_s[m] * HDIM + dir * HHDIM + u);
        }
    }
}

// ---- select + projection via f16 MFMA: 32 words/block, 512 thr (r0-proven) ----
__global__ __launch_bounds__(512, 2)
void proj_k(const int* __restrict__ word_ids, const int* __restrict__ is_oov,
            const float* __restrict__ word_emb, const char* __restrict__ wsb,
            float* __restrict__ out) {
    const int tid = threadIdx.x;
    const int n0 = blockIdx.x * TP;
    __shared__ __align__(16) _Float16 Zp[TP][520];   // 33.3 KB

    for (int f = tid; f < TP * 128; f += 512) {      // 128 segs of 4 elems per word
        int w = f >> 7, s4 = f & 127;
        int n = n0 + w;
        if (is_oov[n] > 0) {
            ushort4 hv = ((const ushort4*)((const unsigned short*)(wsb + B_CHE) + (size_t)n * HDIM))[s4];
            *(ushort4*)&Zp[w][s4 * 4] = hv;
        } else {
            float4 v = ((const float4*)(word_emb + (size_t)word_ids[n] * HDIM))[s4];
            Zp[w][s4 * 4 + 0] = (_Float16)v.x;
            Zp[w][s4 * 4 + 1] = (_Float16)v.y;
            Zp[w][s4 * 4 + 2] = (_Float16)v.z;
            Zp[w][s4 * 4 + 3] = (_Float16)v.w;
        }
    }
    __syncthreads();

    const int wv = tid >> 6, lane = tid & 63, col = lane & 15, quad = lane >> 4;
    const float* pbb = (const float*)(wsb + B_PBB);
    f32x4 acc[4][2];
    #pragma unroll
    for (int c = 0; c < 4; ++c) {
        float b = pbb[wv * 64 + c * 16 + col];
        acc[c][0] = (f32x4){b, b, b, b};
        acc[c][1] = (f32x4){b, b, b, b};
    }

    const uint4* pbf = (const uint4*)(wsb + B_PBF);
    #pragma unroll
    for (int kt = 0; kt < 16; ++kt) {
        f16x8 af0 = *(const f16x8*)&Zp[col][kt * 32 + quad * 8];
        f16x8 af1 = *(const f16x8*)&Zp[16 + col][kt * 32 + quad * 8];
        #pragma unroll
        for (int c = 0; c < 4; ++c) {
            U4H8 b; b.u = pbf[(size_t)kt * 2048 + (wv * 4 + c) * 64 + lane];
            acc[c][0] = __builtin_amdgcn_mfma_f32_16x16x32_f16(af0, b.h, acc[c][0], 0, 0, 0);
            acc[c][1] = __builtin_amdgcn_mfma_f32_16x16x32_f16(af1, b.h, acc[c][1], 0, 0, 0);
        }
    }

    #pragma unroll
    for (int mt = 0; mt < 2; ++mt)
        #pragma unroll
        for (int r = 0; r < 4; ++r) {
            const size_t m = n0 + mt * 16 + quad * 4 + r;
            #pragma unroll
            for (int c = 0; c < 4; ++c)
                __builtin_nontemporal_store(acc[c][mt][r], &out[m * HDIM + wv * 64 + c * 16 + col]);
        }
}

extern "C" void kernel_launch(void* const* d_in, const int* in_sizes, int n_in,
                              void* d_out, int out_size, void* d_ws, size_t ws_size,
                              hipStream_t stream) {
    const int*   word_ids  = (const int*)d_in[0];
    const int*   is_oov    = (const int*)d_in[1];
    const int*   char_ids  = (const int*)d_in[2];
    const int*   char_lens = (const int*)d_in[3];
    const float* word_emb  = (const float*)d_in[4];
    const float* char_emb  = (const float*)d_in[5];
    const float* w_ih_f    = (const float*)d_in[6];
    const float* w_hh_f    = (const float*)d_in[7];
    const float* b_ih_f    = (const float*)d_in[8];
    const float* b_hh_f    = (const float*)d_in[9];
    const float* w_ih_b    = (const float*)d_in[10];
    const float* w_hh_b    = (const float*)d_in[11];
    const float* b_ih_b    = (const float*)d_in[12];
    const float* b_hh_b    = (const float*)d_in[13];
    const float* proj_w    = (const float*)d_in[14];
    const float* proj_b    = (const float*)d_in[15];
    float* out = (float*)d_out;
    char*  wsb = (char*)d_ws;
    int*   ip  = (int*)(wsb + B_INT);

    hipMemsetAsync(ip, 0, 256, stream);
    prep_k<<<256, 256, 0, stream>>>(w_hh_f, w_hh_b, proj_w, proj_b, wsb);
    gxc_k<<<128, 256, 0, stream>>>(w_ih_f, w_ih_b, b_ih_f, b_hh_f, b_ih_b, b_hh_b, char_emb, wsb);
    count_k<<<NWORDS / 256, 256, 0, stream>>>(is_oov, char_lens, ip);
    prefix_k<<<1, 64, 0, stream>>>(ip);
    scatter_k<<<NWORDS / 256, 256, 0, stream>>>(is_oov, char_lens, ip);
    lstm_k<<<512, 512, 0, stream>>>(char_ids, char_lens, wsb, ip);
    proj_k<<<NWORDS / TP, 512, 0, stream>>>(word_ids, is_oov, word_emb, wsb, out);
}